// Round 16
// baseline (218.472 us; speedup 1.0000x reference)
//
#include <hip/hip_runtime.h>
#include <hip/hip_bf16.h>
#include <math.h>

#define SEQ   2048
#define EMBD  2048
#define NH    16
#define NKV   4
#define HD    128
#define NQKV  3072
#define NUNITS 608        // 512 strip-pair units + 96 second-chunks of split units
#define NSPLIT 96         // split units: h>=10 && p>=8 (L>16), 2 KV chunks each

typedef __attribute__((ext_vector_type(8))) short short8;
typedef __attribute__((ext_vector_type(4))) short short4v;
typedef __attribute__((ext_vector_type(4))) float floatx4;

static __device__ __forceinline__ short f2bf(float f) {
    union { float f; unsigned u; } cv; cv.f = f;
    unsigned u = cv.u;
    u += 0x7FFF + ((u >> 16) & 1);   // round-to-nearest-even
    return (short)(u >> 16);
}

// async global->LDS, 16B per lane. LDS dest = wave-uniform base + lane*16.
#define GL16(gsrc, ldst)                                                        \
    __builtin_amdgcn_global_load_lds(                                           \
        (const __attribute__((address_space(1))) void*)(gsrc),                  \
        (__attribute__((address_space(3))) void*)(ldst), 16, 0, 0)

#define MFMA16(a, b, c) __builtin_amdgcn_mfma_f32_16x16x32_bf16(a, b, c, 0, 0, 0)

// ALiBi window in 64-tiles: truncated mass beyond W is < ~0.2% relative
static __device__ __forceinline__ int alibi_window(float slope2) {
    return (int)ceilf((32.0f / slope2 + 63.0f) * (1.0f / 64.0f));
}

// ---------------- fused fp32 -> bf16 convert (all 5 tensors, one launch) ------
__global__ void cvt_all(const float* __restrict__ x,  const float* __restrict__ qw,
                        const float* __restrict__ kw, const float* __restrict__ vw,
                        const float* __restrict__ ow,
                        short* __restrict__ xb, short* __restrict__ wall,
                        short* __restrict__ owb) {
    int i = blockIdx.x * blockDim.x + threadIdx.x;   // quad index, < 4718592
    const float* src; short* dst; int off;
    if (i < 2097152)      { src = x;  dst = xb;             off = i; }
    else if (i < 3145728) { src = qw; dst = wall;           off = i - 2097152; }
    else if (i < 3407872) { src = kw; dst = wall + 4194304; off = i - 3145728; }
    else if (i < 3670016) { src = vw; dst = wall + 5242880; off = i - 3407872; }
    else                  { src = ow; dst = owb;            off = i - 3670016; }
    float4 v = ((const float4*)src)[off];
    float a[4] = {v.x, v.y, v.z, v.w};
    short4v o;
#pragma unroll
    for (int j = 0; j < 4; ++j) {
        float f = a[j];
        f = isnan(f) ? 0.0f : fminf(fmaxf(f, -10000.0f), 10000.0f);
        o[j] = f2bf(f);
    }
    ((short4v*)dst)[off] = o;
}

// ---------------- work-queue setup (unchanged from R15) -----------------------
__global__ void attn_setup(int* __restrict__ qtab) {
    __shared__ int keys[NUNITS];
    const int i = threadIdx.x;           // 640 threads, 608 active
    int key = 0, enc = 0;
    if (i < NUNITS) {
        int b, h, p, c;
        if (i < 512) { b = i >> 8; h = (i >> 4) & 15; p = i & 15; c = 0; }
        else { int j = i - 512; b = j / 48; int r2 = j % 48; h = 10 + r2 / 8; p = 8 + r2 % 8; c = 1; }
        float slope2 = exp2f(-0.5f * (float)(h + 1)) * 1.44269504f;
        int W = alibi_window(slope2);
        int L = min(W + 1, 2 * p + 2);
        bool split = (h >= 10) && (p >= 8);
        int n0 = (L + 1) >> 1;
        int cost = split ? (c == 0 ? n0 : L - n0) : L;
        enc = (c << 9) | (b << 8) | (h << 4) | p;
        key = cost * 1024 + i;
        keys[i] = key;
    }
    __syncthreads();
    if (i < NUNITS) {
        int rank = 0;
        for (int j = 0; j < NUNITS; ++j) rank += (keys[j] > key);
        qtab[rank] = enc;
    }
    if (i == 0) qtab[NUNITS] = 0;
}

// ---------------- bf16 GEMM: 256x128 tile, BK=64, 8-wave, 4-phase pipeline ----
// Per K-tile: 4 phases, each {ds_read subtile || 2x global_load_lds prefetch ->
// s_barrier -> setprio(1) 8xMFMA setprio(0) -> s_barrier}; one __syncthreads
// per tile hands off the double buffer (drains prefetch; cover = whole tile).
// Staging/fragment/swizzle formulas identical to the verified BK=64 kernel.
// MODE 0: scatter epilogue -> Q (pre-scaled by scale*log2e), K, VT (bf16)
// MODE 1: plain fp32 store
template<int MODE>
__global__ __launch_bounds__(512) void gemm_bt(
    const short* __restrict__ A, const short* __restrict__ W,
    float* __restrict__ Cout, int M, int N, int K,
    short* __restrict__ qb, short* __restrict__ kb, short* __restrict__ vb)
{
    __shared__ __align__(16) short sA[2][256 * 64];   // 64 KB
    __shared__ __align__(16) short sB[2][128 * 64];   // 32 KB

    const int tid  = threadIdx.x;
    const int lane = tid & 63;
    const int wv   = tid >> 6;                  // 8 waves
    const int wr   = wv >> 1, wc = wv & 1;      // 4x2 wave grid, 64x64 per wave
    const int lr   = lane & 15, lg = lane >> 4;
    const int bn   = blockIdx.x, bm = blockIdx.y;

    // staging: A = 2048 chunks(16B) -> 4/thread; B = 1024 -> 2/thread
    const short* gA[4]; const short* gB[2];
    int aOff[4], bOff[2];
#pragma unroll
    for (int s = 0; s < 4; ++s) {
        int ck = s * 512 + tid;
        int row = ck >> 3, seg = ck & 7;        // 8x16B chunks per 64-short row
        gA[s] = A + (size_t)(bm * 256 + row) * K + (seg ^ (row & 7)) * 8;
        aOff[s] = ck * 8;
    }
#pragma unroll
    for (int s = 0; s < 2; ++s) {
        int ck = s * 512 + tid;
        int row = ck >> 3, seg = ck & 7;
        gB[s] = W + (size_t)(bn * 128 + row) * K + (seg ^ (row & 7)) * 8;
        bOff[s] = ck * 8;
    }

    floatx4 acc[4][4] = {};
    const int nkt = K / 64;

    // prologue: stage tile 0 into buf 0
#pragma unroll
    for (int s = 0; s < 4; ++s) GL16(gA[s], &sA[0][0] + aOff[s]);
#pragma unroll
    for (int s = 0; s < 2; ++s) GL16(gB[s], &sB[0][0] + bOff[s]);
    __syncthreads();

#pragma unroll 1
    for (int kt = 0; kt < nkt; ++kt) {
        const int cur = kt & 1;
        const short* a_ = &sA[cur][0];
        const short* b_ = &sB[cur][0];
        short* an = &sA[cur ^ 1][0];
        short* bnx = &sB[cur ^ 1][0];
        const bool pf = (kt + 1 < nkt);
        const int ko = (kt + 1) * 64;

        short8 afA, afB, bfr[4];

        // ---- phase 0: ks=0, A rows 0,1 + all B@ks0; prefetch 2
        {
            int ra0 = wr * 64 + lr, ra1 = wr * 64 + 16 + lr;
            afA = *(const short8*)&a_[ra0 * 64 + ((lg ^ (ra0 & 7)) * 8)];
            afB = *(const short8*)&a_[ra1 * 64 + ((lg ^ (ra1 & 7)) * 8)];
#pragma unroll
            for (int j = 0; j < 4; ++j) {
                int rb = wc * 64 + j * 16 + lr;
                bfr[j] = *(const short8*)&b_[rb * 64 + ((lg ^ (rb & 7)) * 8)];
            }
            if (pf) { GL16(gA[0] + ko, an + aOff[0]); GL16(gA[1] + ko, an + aOff[1]); }
            __builtin_amdgcn_s_barrier();
            __builtin_amdgcn_s_setprio(1);
#pragma unroll
            for (int j = 0; j < 4; ++j) {
                acc[0][j] = MFMA16(afA, bfr[j], acc[0][j]);
                acc[1][j] = MFMA16(afB, bfr[j], acc[1][j]);
            }
            __builtin_amdgcn_s_setprio(0);
            __builtin_amdgcn_s_barrier();
        }
        // ---- phase 1: ks=0, A rows 2,3 (reuse bfr); prefetch 2
        {
            int ra2 = wr * 64 + 32 + lr, ra3 = wr * 64 + 48 + lr;
            afA = *(const short8*)&a_[ra2 * 64 + ((lg ^ (ra2 & 7)) * 8)];
            afB = *(const short8*)&a_[ra3 * 64 + ((lg ^ (ra3 & 7)) * 8)];
            if (pf) { GL16(gA[2] + ko, an + aOff[2]); GL16(gA[3] + ko, an + aOff[3]); }
            __builtin_amdgcn_s_barrier();
            __builtin_amdgcn_s_setprio(1);
#pragma unroll
            for (int j = 0; j < 4; ++j) {
                acc[2][j] = MFMA16(afA, bfr[j], acc[2][j]);
                acc[3][j] = MFMA16(afB, bfr[j], acc[3][j]);
            }
            __builtin_amdgcn_s_setprio(0);
            __builtin_amdgcn_s_barrier();
        }
        // ---- phase 2: ks=1, A rows 0,1 + all B@ks1; prefetch 2 (B)
        {
            int ra0 = wr * 64 + lr, ra1 = wr * 64 + 16 + lr;
            afA = *(const short8*)&a_[ra0 * 64 + (((4 + lg) ^ (ra0 & 7)) * 8)];
            afB = *(const short8*)&a_[ra1 * 64 + (((4 + lg) ^ (ra1 & 7)) * 8)];
#pragma unroll
            for (int j = 0; j < 4; ++j) {
                int rb = wc * 64 + j * 16 + lr;
                bfr[j] = *(const short8*)&b_[rb * 64 + (((4 + lg) ^ (rb & 7)) * 8)];
            }
            if (pf) { GL16(gB[0] + ko, bnx + bOff[0]); GL16(gB[1] + ko, bnx + bOff[1]); }
            __builtin_amdgcn_s_barrier();
            __builtin_amdgcn_s_setprio(1);
#pragma unroll
            for (int j = 0; j < 4; ++j) {
                acc[0][j] = MFMA16(afA, bfr[j], acc[0][j]);
                acc[1][j] = MFMA16(afB, bfr[j], acc[1][j]);
            }
            __builtin_amdgcn_s_setprio(0);
            __builtin_amdgcn_s_barrier();
        }
        // ---- phase 3: ks=1, A rows 2,3 (reuse bfr)
        {
            int ra2 = wr * 64 + 32 + lr, ra3 = wr * 64 + 48 + lr;
            afA = *(const short8*)&a_[ra2 * 64 + (((4 + lg) ^ (ra2 & 7)) * 8)];
            afB = *(const short8*)&a_[ra3 * 64 + (((4 + lg) ^ (ra3 & 7)) * 8)];
            __builtin_amdgcn_s_barrier();
            __builtin_amdgcn_s_setprio(1);
#pragma unroll
            for (int j = 0; j < 4; ++j) {
                acc[2][j] = MFMA16(afA, bfr[j], acc[2][j]);
                acc[3][j] = MFMA16(afB, bfr[j], acc[3][j]);
            }
            __builtin_amdgcn_s_setprio(0);
        }
        __syncthreads();   // tile handoff: drains prefetch vmcnt + lgkm
    }

    const float QSCALE = 0.08838834764831845f * 1.44269504f;  // scale * log2e
#pragma unroll
    for (int i = 0; i < 4; ++i)
#pragma unroll
        for (int j = 0; j < 4; ++j)
#pragma unroll
            for (int r = 0; r < 4; ++r) {
                int gm = bm * 256 + wr * 64 + i * 16 + lg * 4 + r;
                int gn = bn * 128 + wc * 64 + j * 16 + lr;
                float v = acc[i][j][r];
                if (MODE == 0) {
                    int b = gm >> 11, t = gm & (SEQ - 1);
                    if (gn < 2048) {
                        int h = gn >> 7, d = gn & 127;
                        qb[(((size_t)(b * NH + h)) * SEQ + t) * HD + d] = f2bf(v * QSCALE);
                    } else if (gn < 2560) {
                        int hk = (gn - 2048) >> 7, d = gn & 127;
                        kb[(((size_t)(b * NKV + hk)) * SEQ + t) * HD + d] = f2bf(v);
                    } else {
                        int hv = (gn - 2560) >> 7, d = gn & 127;
                        vb[(((size_t)(b * NKV + hv)) * HD + d) * SEQ + t] = f2bf(v);
                    }
                } else {
                    Cout[(size_t)gm * N + gn] = v;
                }
            }
}

// ---------------- flash attention (R15, unchanged) ----------------------------
__global__ __launch_bounds__(512, 4) void attn_fwd(
    const short* __restrict__ Q, const short* __restrict__ Kg,
    const short* __restrict__ VT, short* __restrict__ Y,
    float* __restrict__ part, int* __restrict__ qtab)
{
    __shared__ __align__(16) short sK[2][64 * 128];   // 32 KB, swizzled chunks
    __shared__ __align__(16) short sV[128 * 64];      // 16 KB, swizzled chunks
    __shared__ short Plds[8][16][72];                 // 18 KB
    __shared__ int s_unit;

    const int tid  = threadIdx.x;
    const int wave = tid >> 6, lane = tid & 63;
    const int lr = lane & 15, lg = lane >> 4;
    int* qcnt = qtab + NUNITS;

    int lOff[2];
#pragma unroll
    for (int j = 0; j < 2; ++j)
        lOff[j] = (wave * 128 + j * 64 + lane) * 8;   // lane-linear, 16B chunks

    for (;;) {
        if (tid == 0) {
            int r = atomicAdd(qcnt, 1);
            s_unit = (r < NUNITS) ? qtab[r] : -1;
        }
        __syncthreads();
        const int enc = s_unit;
        __syncthreads();
        if (enc < 0) break;

        const int c = (enc >> 9) & 1, b = (enc >> 8) & 1;
        const int h = (enc >> 4) & 15, p = enc & 15;
        const int hkv = h >> 2;               // repeat_interleave: head h -> kv h/4
        const int qgw = 2 * p + (wave < 4 ? 1 : 0);   // this wave's strip

        const short* Qb = Q  +  ((size_t)(b * NH  + h  )) * SEQ * HD;
        const short* Kp = Kg +  ((size_t)(b * NKV + hkv)) * SEQ * HD;
        const short* Vp = VT +  ((size_t)(b * NKV + hkv)) * HD * SEQ;

        const float slope2 = exp2f(-0.5f * (float)(h + 1)) * 1.44269504f;
        const int W = alibi_window(slope2);
        const int thi = 2 * p + 1;
        const int L = min(W + 1, 2 * p + 2);
        const bool split = (h >= 10) && (p >= 8);
        const int n0 = (L + 1) >> 1;
        int t1, t0;
        if (!split)      { t1 = thi;      t0 = thi - L + 1; }
        else if (c == 0) { t1 = thi;      t0 = thi - n0 + 1; }
        else             { t1 = thi - n0; t0 = thi - L + 1; }

        const short* gK[2]; const short* gV[2];
#pragma unroll
        for (int j = 0; j < 2; ++j) {
            int ck = wave * 128 + j * 64 + lane;
            int krow = ck >> 4, kseg = ck & 15;
            gK[j] = Kp + (size_t)krow * HD + (kseg ^ (krow & 7)) * 8;   // pre-swz src
            int vrow = ck >> 3, vseg = ck & 7;
            gV[j] = Vp + (size_t)vrow * SEQ + (vseg ^ (vrow & 7)) * 8;
        }

        float c_nt[4];
#pragma unroll
        for (int nt = 0; nt < 4; ++nt) c_nt[nt] = slope2 * (float)(nt * 16 + lr);

        const int q0 = qgw * 64 + (wave & 3) * 16;
        short8 qf[4];
#pragma unroll
        for (int cc = 0; cc < 4; ++cc)
            qf[cc] = *(const short8*)&Qb[(size_t)(q0 + lr) * HD + cc * 32 + lg * 8];

        floatx4 po[8] = {};
        float m[4], lsum[4];
#pragma unroll
        for (int r = 0; r < 4; ++r) { m[r] = -3.0e38f; lsum[r] = 0.0f; }

        int cur = 0;
        // prologue: stage K(t1)
#pragma unroll
        for (int j = 0; j < 2; ++j)
            GL16(gK[j] + (size_t)(t1 << 6) * HD, &sK[0][0] + lOff[j]);
        __syncthreads();

#pragma unroll 1
        for (int t = t1; t >= t0; --t) {
            // stage V(t); prefetch K(t-1) into other K buffer
#pragma unroll
            for (int j = 0; j < 2; ++j)
                GL16(gV[j] + (t << 6), &sV[0] + lOff[j]);
            if (t > t0) {
#pragma unroll
                for (int j = 0; j < 2; ++j)
                    GL16(gK[j] + (size_t)((t - 1) << 6) * HD, &sK[cur ^ 1][0] + lOff[j]);
            }

            const bool active = (t <= qgw) && (t > qgw - W);
            const int kv0 = t << 6;

            if (active) {
                const short* kr = &sK[cur][0];
                floatx4 sf[4];
                __builtin_amdgcn_s_setprio(1);
#pragma unroll
                for (int nt = 0; nt < 4; ++nt) {
                    floatx4 sacc = {0.f, 0.f, 0.f, 0.f};
#pragma unroll
                    for (int cc = 0; cc < 4; ++cc) {
                        int krow = nt * 16 + lr;
                        short8 kf = *(const short8*)&kr[krow * 128 + (((cc * 4 + lg) ^ (krow & 7)) * 8)];
                        sacc = __builtin_amdgcn_mfma_f32_16x16x32_bf16(qf[cc], kf, sacc, 0, 0, 0);
                    }
                    sf[nt] = sacc;
                }
                __builtin_amdgcn_s_setprio(0);

                const float a2t = slope2 * (float)kv0;
                const bool masked = (t == qgw);
#pragma unroll
                for (int r = 0; r < 4; ++r) {
                    const int qpos = q0 + lg * 4 + r;
                    float sv[4];
#pragma unroll
                    for (int nt = 0; nt < 4; ++nt)
                        sv[nt] = sf[nt][r] + a2t + c_nt[nt];   // base-2 score
                    if (masked) {
#pragma unroll
                        for (int nt = 0; nt < 4; ++nt) {
                            int kpos = kv0 + nt * 16 + lr;
                            if (kpos > qpos) sv[nt] = -3.0e38f;
                        }
                    }
                    bool over = (sv[0] > m[r]) | (sv[1] > m[r]) | (sv[2] > m[r]) | (sv[3] > m[r]);
                    if (__any(over)) {
                        float mx = fmaxf(fmaxf(sv[0], sv[1]), fmaxf(sv[2], sv[3]));
#pragma unroll
                        for (int off = 1; off < 16; off <<= 1) mx = fmaxf(mx, __shfl_xor(mx, off));
                        float mn = fmaxf(m[r], mx);
                        float rs = exp2f(m[r] - mn);
                        lsum[r] *= rs;
#pragma unroll
                        for (int dt = 0; dt < 8; ++dt) po[dt][r] *= rs;
                        m[r] = mn;
                    }
#pragma unroll
                    for (int nt = 0; nt < 4; ++nt) {
                        float pp = exp2f(sv[nt] - m[r]);
                        lsum[r] += pp;
                        Plds[wave][lg * 4 + r][nt * 16 + lr] = f2bf(pp);
                    }
                }
            }

            __syncthreads();   // barrier 1: V(t) (and K(t-1)) staged

            if (active) {
                short8 pf0 = *(const short8*)&Plds[wave][lr][lg * 8];
                short8 pf1 = *(const short8*)&Plds[wave][lr][32 + lg * 8];
                __builtin_amdgcn_s_setprio(1);
#pragma unroll
                for (int dt = 0; dt < 8; ++dt) {
                    int vrow = dt * 16 + lr;
                    short8 vf0 = *(const short8*)&sV[vrow * 64 + (((lg    ) ^ (vrow & 7)) * 8)];
                    short8 vf1 = *(const short8*)&sV[vrow * 64 + (((lg + 4) ^ (vrow & 7)) * 8)];
                    po[dt] = __builtin_amdgcn_mfma_f32_16x16x32_bf16(pf0, vf0, po[dt], 0, 0, 0);
                    po[dt] = __builtin_amdgcn_mfma_f32_16x16x32_bf16(pf1, vf1, po[dt], 0, 0, 0);
                }
                __builtin_amdgcn_s_setprio(0);
            }

            __syncthreads();   // barrier 2: sV and sK[cur] free for next iteration
            cur ^= 1;
        }

        if (!split) {
#pragma unroll
            for (int r = 0; r < 4; ++r) {
                float sum = lsum[r];
#pragma unroll
                for (int off = 1; off < 16; off <<= 1) sum += __shfl_xor(sum, off);
                float inv = 1.0f / sum;
                int row = q0 + lg * 4 + r;
#pragma unroll
                for (int dt = 0; dt < 8; ++dt)
                    Y[((size_t)(b * SEQ + row)) * EMBD + h * HD + dt * 16 + lr] = f2bf(po[dt][r] * inv);
            }
        } else {
            int jslot = b * 48 + (h - 10) * 8 + (p - 8);
            float* pw = part + (size_t)(jslot * 2 + c) * (128 * 130);
#pragma unroll
            for (int r = 0; r < 4; ++r) {
                float sum = lsum[r];
#pragma unroll
                for (int off = 1; off < 16; off <<= 1) sum += __shfl_xor(sum, off);
                int rr = wave * 16 + lg * 4 + r;
#pragma unroll
                for (int dt = 0; dt < 8; ++dt)
                    pw[rr * 130 + dt * 16 + lr] = po[dt][r];
                if (lr == 0) { pw[rr * 130 + 128] = m[r]; pw[rr * 130 + 129] = sum; }
            }
        }
    }
}

// ---------------- combine partial chunks (96 split units x 128 rows) ----------
__global__ void attn_combine(const float* __restrict__ part, short* __restrict__ Y) {
    const int tid = threadIdx.x;
    const int rg  = blockIdx.x * 2 + (tid >> 7);   // 0..12287
    const int col = tid & 127;
    const int j = rg >> 7, rr = rg & 127;
    const int b = j / 48; const int r2 = j % 48;
    const int h = 10 + r2 / 8, p = 8 + r2 % 8;

    const float* p0 = part + ((size_t)(j * 2) * 128 + rr) * 130;
    const float* p1 = p0 + 128 * 130;
    float m0 = p0[128], l0 = p0[129];
    float m1 = p1[128], l1 = p1[129];
    float M = fmaxf(m0, m1);
    float s0 = exp2f(m0 - M), s1 = exp2f(m1 - M);
    float v = (p0[col] * s0 + p1[col] * s1) / (l0 * s0 + l1 * s1);

    const int w = rr >> 4, i2 = rr & 15;
    const int grow = (w < 4 ? (2 * p + 1) : (2 * p)) * 64 + (w & 3) * 16 + i2;
    Y[((size_t)(b * SEQ + grow)) * EMBD + h * HD + col] = f2bf(v);
}

// ---------------- launch ----------------
extern "C" void kernel_launch(void* const* d_in, const int* in_sizes, int n_in,
                              void* d_out, int out_size, void* d_ws, size_t ws_size,
                              hipStream_t stream) {
    const float* x   = (const float*)d_in[0];
    const float* q_w = (const float*)d_in[1];
    const float* k_w = (const float*)d_in[2];
    const float* v_w = (const float*)d_in[3];
    const float* o_w = (const float*)d_in[4];
    float* out = (float*)d_out;

    char* ws = (char*)d_ws;
    short* x_bf  = (short*)(ws);                       // 4096x2048      16.8MB
    short* w_all = (short*)(ws + 16777216);            // 3072x2048      12.6MB
    short* o_wb  = (short*)(ws + 29360128);            // 2048x2048       8.4MB
    short* q_b   = (short*)(ws + 37748736);            // [2,16,2048,128] 16.8MB
    short* k_b   = (short*)(ws + 54525952);            // [2,4,2048,128]  4.2MB
    short* vT_b  = (short*)(ws + 58720256);            // [2,4,128,2048]  4.2MB
    short* y_b   = (short*)(ws + 62914560);            // 4096x2048      16.8MB
    int*   qtab  = (int*)(ws);                         // queue (dead x_bf region)
    float* part  = (float*)(ws + 65536);               // partials: 12.8MB, same hole

    cvt_all<<<18432, 256, 0, stream>>>(x, q_w, k_w, v_w, o_w, x_bf, w_all, o_wb);

    gemm_bt<0><<<dim3(NQKV / 128, 4096 / 256), 512, 0, stream>>>(
        x_bf, w_all, nullptr, 4096, NQKV, EMBD, q_b, k_b, vT_b);

    attn_setup<<<1, 640, 0, stream>>>(qtab);           // after gemm<0>: x_bf dead
    attn_fwd<<<512, 512, 0, stream>>>(q_b, k_b, vT_b, y_b, part, qtab);
    attn_combine<<<6144, 256, 0, stream>>>(part, y_b);

    gemm_bt<1><<<dim3(EMBD / 128, 4096 / 256), 512, 0, stream>>>(
        y_b, o_wb, out, 4096, EMBD, EMBD, nullptr, nullptr, nullptr);
}

// Round 17
// 216.637 us; speedup vs baseline: 1.0085x; 1.0085x over previous
//
#include <hip/hip_runtime.h>
#include <hip/hip_bf16.h>
#include <math.h>

#define SEQ   2048
#define EMBD  2048
#define NH    16
#define NKV   4
#define HD    128
#define NQKV  3072
#define NUNITS 608        // 512 strip-pair units + 96 second-chunks of split units
#define NSPLIT 96         // split units: h>=10 && p>=8 (L>16), 2 KV chunks each

typedef __attribute__((ext_vector_type(8))) short short8;
typedef __attribute__((ext_vector_type(4))) short short4v;
typedef __attribute__((ext_vector_type(4))) float floatx4;

static __device__ __forceinline__ short f2bf(float f) {
    union { float f; unsigned u; } cv; cv.f = f;
    unsigned u = cv.u;
    u += 0x7FFF + ((u >> 16) & 1);   // round-to-nearest-even
    return (short)(u >> 16);
}

// async global->LDS, 16B per lane. LDS dest = wave-uniform base + lane*16.
#define GL16(gsrc, ldst)                                                        \
    __builtin_amdgcn_global_load_lds(                                           \
        (const __attribute__((address_space(1))) void*)(gsrc),                  \
        (__attribute__((address_space(3))) void*)(ldst), 16, 0, 0)

// ALiBi window in 64-tiles: truncated mass beyond W is < ~0.2% relative
static __device__ __forceinline__ int alibi_window(float slope2) {
    return (int)ceilf((32.0f / slope2 + 63.0f) * (1.0f / 64.0f));
}

// ---------------- fused fp32 -> bf16 convert (all 5 tensors, one launch) ------
__global__ void cvt_all(const float* __restrict__ x,  const float* __restrict__ qw,
                        const float* __restrict__ kw, const float* __restrict__ vw,
                        const float* __restrict__ ow,
                        short* __restrict__ xb, short* __restrict__ wall,
                        short* __restrict__ owb) {
    int i = blockIdx.x * blockDim.x + threadIdx.x;   // quad index, < 4718592
    const float* src; short* dst; int off;
    if (i < 2097152)      { src = x;  dst = xb;             off = i; }
    else if (i < 3145728) { src = qw; dst = wall;           off = i - 2097152; }
    else if (i < 3407872) { src = kw; dst = wall + 4194304; off = i - 3145728; }
    else if (i < 3670016) { src = vw; dst = wall + 5242880; off = i - 3407872; }
    else                  { src = ow; dst = owb;            off = i - 3670016; }
    float4 v = ((const float4*)src)[off];
    float a[4] = {v.x, v.y, v.z, v.w};
    short4v o;
#pragma unroll
    for (int j = 0; j < 4; ++j) {
        float f = a[j];
        f = isnan(f) ? 0.0f : fminf(fmaxf(f, -10000.0f), 10000.0f);
        o[j] = f2bf(f);
    }
    ((short4v*)dst)[off] = o;
}

// ---------------- work-queue setup (unchanged from R15) -----------------------
__global__ void attn_setup(int* __restrict__ qtab) {
    __shared__ int keys[NUNITS];
    const int i = threadIdx.x;           // 640 threads, 608 active
    int key = 0, enc = 0;
    if (i < NUNITS) {
        int b, h, p, c;
        if (i < 512) { b = i >> 8; h = (i >> 4) & 15; p = i & 15; c = 0; }
        else { int j = i - 512; b = j / 48; int r2 = j % 48; h = 10 + r2 / 8; p = 8 + r2 % 8; c = 1; }
        float slope2 = exp2f(-0.5f * (float)(h + 1)) * 1.44269504f;
        int W = alibi_window(slope2);
        int L = min(W + 1, 2 * p + 2);
        bool split = (h >= 10) && (p >= 8);
        int n0 = (L + 1) >> 1;
        int cost = split ? (c == 0 ? n0 : L - n0) : L;
        enc = (c << 9) | (b << 8) | (h << 4) | p;
        key = cost * 1024 + i;
        keys[i] = key;
    }
    __syncthreads();
    if (i < NUNITS) {
        int rank = 0;
        for (int j = 0; j < NUNITS; ++j) rank += (keys[j] > key);
        qtab[rank] = enc;
    }
    if (i == 0) qtab[NUNITS] = 0;
}

// ---------------- bf16 GEMM: 128x128 tile, BK=64, swizzled LDS, dbuf ----------
// R15 body + double buffer with ONE __syncthreads per K-tile: barrier -> issue
// prefetch(kt+1 -> buf^1) -> compute(buf[cur]). The next tile's top barrier
// drains the prefetch AFTER a full compute phase (~1500cyc > ~900cyc HBM
// latency) -> drain ~ free, barrier count halved. LDS 64KB -> 2 blocks/CU.
// MODE 0: scatter epilogue -> Q (pre-scaled by scale*log2e), K, VT (bf16)
// MODE 1: plain fp32 store
template<int MODE>
__global__ __launch_bounds__(256) void gemm_bt(
    const short* __restrict__ A, const short* __restrict__ W,
    float* __restrict__ Cout, int M, int N, int K,
    short* __restrict__ qb, short* __restrict__ kb, short* __restrict__ vb)
{
    __shared__ __align__(16) short sA[2][128 * 64];   // 32 KB
    __shared__ __align__(16) short sB[2][128 * 64];   // 32 KB

    const int tid  = threadIdx.x;
    const int lane = tid & 63;
    const int wv   = tid >> 6;
    const int wr   = wv >> 1, wc = wv & 1;       // 2x2 wave grid, 64x64 each
    const int lr   = lane & 15, lg = lane >> 4;
    const int bn   = blockIdx.x, bm = blockIdx.y;

    // staging: 1024 chunks(16B) per matrix; wave w covers [w*256, w*256+256)
    const short* gA[4]; const short* gB[4];
    int sOff[4];
#pragma unroll
    for (int s = 0; s < 4; ++s) {
        int ck  = wv * 256 + s * 64 + lane;
        int row = ck >> 3, seg = ck & 7;         // 8x16B chunks per 64-short row
        int segSw = seg ^ (row & 7);             // pre-swizzled source column
        gA[s] = A + (size_t)(bm * 128 + row) * K + segSw * 8;
        gB[s] = W + (size_t)(bn * 128 + row) * K + segSw * 8;
        sOff[s] = (wv * 256 + s * 64) * 8;       // wave-uniform linear dest base
    }

    floatx4 acc[4][4] = {};
    const int nkt = K / 64;

    // prologue: stage tile 0 into buf 0
#pragma unroll
    for (int s = 0; s < 4; ++s) {
        GL16(gA[s], &sA[0][0] + sOff[s]);
        GL16(gB[s], &sB[0][0] + sOff[s]);
    }

    int cur = 0;
#pragma unroll 1
    for (int kt = 0; kt < nkt; ++kt) {
        __syncthreads();   // buf[cur] valid (loads had full prev tile to land);
                           // all reads of buf[cur^1] complete -> safe to overwrite
        if (kt + 1 < nkt) {
#pragma unroll
            for (int s = 0; s < 4; ++s) {
                GL16(gA[s] + (kt + 1) * 64, &sA[cur ^ 1][0] + sOff[s]);
                GL16(gB[s] + (kt + 1) * 64, &sB[cur ^ 1][0] + sOff[s]);
            }
        }

        const short* a_ = &sA[cur][0];
        const short* b_ = &sB[cur][0];
#pragma unroll
        for (int ks = 0; ks < 2; ++ks) {
            short8 af[4], bfr[4];
#pragma unroll
            for (int i = 0; i < 4; ++i) {
                int ra = wr * 64 + i * 16 + lr;
                int rb = wc * 64 + i * 16 + lr;
                af[i]  = *(const short8*)&a_[ra * 64 + (((ks * 4 + lg) ^ (ra & 7)) * 8)];
                bfr[i] = *(const short8*)&b_[rb * 64 + (((ks * 4 + lg) ^ (rb & 7)) * 8)];
            }
#pragma unroll
            for (int i = 0; i < 4; ++i)
#pragma unroll
                for (int j = 0; j < 4; ++j)
                    acc[i][j] = __builtin_amdgcn_mfma_f32_16x16x32_bf16(af[i], bfr[j], acc[i][j], 0, 0, 0);
        }
        cur ^= 1;
    }

    const float QSCALE = 0.08838834764831845f * 1.44269504f;  // scale * log2e
#pragma unroll
    for (int i = 0; i < 4; ++i)
#pragma unroll
        for (int j = 0; j < 4; ++j)
#pragma unroll
            for (int r = 0; r < 4; ++r) {
                int gm = bm * 128 + wr * 64 + i * 16 + lg * 4 + r;
                int gn = bn * 128 + wc * 64 + j * 16 + lr;
                float v = acc[i][j][r];
                if (MODE == 0) {
                    int b = gm >> 11, t = gm & (SEQ - 1);
                    if (gn < 2048) {
                        int h = gn >> 7, d = gn & 127;
                        qb[(((size_t)(b * NH + h)) * SEQ + t) * HD + d] = f2bf(v * QSCALE);
                    } else if (gn < 2560) {
                        int hk = (gn - 2048) >> 7, d = gn & 127;
                        kb[(((size_t)(b * NKV + hk)) * SEQ + t) * HD + d] = f2bf(v);
                    } else {
                        int hv = (gn - 2560) >> 7, d = gn & 127;
                        vb[(((size_t)(b * NKV + hv)) * HD + d) * SEQ + t] = f2bf(v);
                    }
                } else {
                    Cout[(size_t)gm * N + gn] = v;
                }
            }
}

// ---------------- flash attention (R15, unchanged) ----------------------------
__global__ __launch_bounds__(512, 4) void attn_fwd(
    const short* __restrict__ Q, const short* __restrict__ Kg,
    const short* __restrict__ VT, short* __restrict__ Y,
    float* __restrict__ part, int* __restrict__ qtab)
{
    __shared__ __align__(16) short sK[2][64 * 128];   // 32 KB, swizzled chunks
    __shared__ __align__(16) short sV[128 * 64];      // 16 KB, swizzled chunks
    __shared__ short Plds[8][16][72];                 // 18 KB
    __shared__ int s_unit;

    const int tid  = threadIdx.x;
    const int wave = tid >> 6, lane = tid & 63;
    const int lr = lane & 15, lg = lane >> 4;
    int* qcnt = qtab + NUNITS;

    int lOff[2];
#pragma unroll
    for (int j = 0; j < 2; ++j)
        lOff[j] = (wave * 128 + j * 64 + lane) * 8;   // lane-linear, 16B chunks

    for (;;) {
        if (tid == 0) {
            int r = atomicAdd(qcnt, 1);
            s_unit = (r < NUNITS) ? qtab[r] : -1;
        }
        __syncthreads();
        const int enc = s_unit;
        __syncthreads();
        if (enc < 0) break;

        const int c = (enc >> 9) & 1, b = (enc >> 8) & 1;
        const int h = (enc >> 4) & 15, p = enc & 15;
        const int hkv = h >> 2;               // repeat_interleave: head h -> kv h/4
        const int qgw = 2 * p + (wave < 4 ? 1 : 0);   // this wave's strip

        const short* Qb = Q  +  ((size_t)(b * NH  + h  )) * SEQ * HD;
        const short* Kp = Kg +  ((size_t)(b * NKV + hkv)) * SEQ * HD;
        const short* Vp = VT +  ((size_t)(b * NKV + hkv)) * HD * SEQ;

        const float slope2 = exp2f(-0.5f * (float)(h + 1)) * 1.44269504f;
        const int W = alibi_window(slope2);
        const int thi = 2 * p + 1;
        const int L = min(W + 1, 2 * p + 2);
        const bool split = (h >= 10) && (p >= 8);
        const int n0 = (L + 1) >> 1;
        int t1, t0;
        if (!split)      { t1 = thi;      t0 = thi - L + 1; }
        else if (c == 0) { t1 = thi;      t0 = thi - n0 + 1; }
        else             { t1 = thi - n0; t0 = thi - L + 1; }

        const short* gK[2]; const short* gV[2];
#pragma unroll
        for (int j = 0; j < 2; ++j) {
            int ck = wave * 128 + j * 64 + lane;
            int krow = ck >> 4, kseg = ck & 15;
            gK[j] = Kp + (size_t)krow * HD + (kseg ^ (krow & 7)) * 8;   // pre-swz src
            int vrow = ck >> 3, vseg = ck & 7;
            gV[j] = Vp + (size_t)vrow * SEQ + (vseg ^ (vrow & 7)) * 8;
        }

        float c_nt[4];
#pragma unroll
        for (int nt = 0; nt < 4; ++nt) c_nt[nt] = slope2 * (float)(nt * 16 + lr);

        const int q0 = qgw * 64 + (wave & 3) * 16;
        short8 qf[4];
#pragma unroll
        for (int cc = 0; cc < 4; ++cc)
            qf[cc] = *(const short8*)&Qb[(size_t)(q0 + lr) * HD + cc * 32 + lg * 8];

        floatx4 po[8] = {};
        float m[4], lsum[4];
#pragma unroll
        for (int r = 0; r < 4; ++r) { m[r] = -3.0e38f; lsum[r] = 0.0f; }

        int cur = 0;
        // prologue: stage K(t1)
#pragma unroll
        for (int j = 0; j < 2; ++j)
            GL16(gK[j] + (size_t)(t1 << 6) * HD, &sK[0][0] + lOff[j]);
        __syncthreads();

#pragma unroll 1
        for (int t = t1; t >= t0; --t) {
            // stage V(t); prefetch K(t-1) into other K buffer
#pragma unroll
            for (int j = 0; j < 2; ++j)
                GL16(gV[j] + (t << 6), &sV[0] + lOff[j]);
            if (t > t0) {
#pragma unroll
                for (int j = 0; j < 2; ++j)
                    GL16(gK[j] + (size_t)((t - 1) << 6) * HD, &sK[cur ^ 1][0] + lOff[j]);
            }

            const bool active = (t <= qgw) && (t > qgw - W);
            const int kv0 = t << 6;

            if (active) {
                const short* kr = &sK[cur][0];
                floatx4 sf[4];
                __builtin_amdgcn_s_setprio(1);
#pragma unroll
                for (int nt = 0; nt < 4; ++nt) {
                    floatx4 sacc = {0.f, 0.f, 0.f, 0.f};
#pragma unroll
                    for (int cc = 0; cc < 4; ++cc) {
                        int krow = nt * 16 + lr;
                        short8 kf = *(const short8*)&kr[krow * 128 + (((cc * 4 + lg) ^ (krow & 7)) * 8)];
                        sacc = __builtin_amdgcn_mfma_f32_16x16x32_bf16(qf[cc], kf, sacc, 0, 0, 0);
                    }
                    sf[nt] = sacc;
                }
                __builtin_amdgcn_s_setprio(0);

                const float a2t = slope2 * (float)kv0;
                const bool masked = (t == qgw);
#pragma unroll
                for (int r = 0; r < 4; ++r) {
                    const int qpos = q0 + lg * 4 + r;
                    float sv[4];
#pragma unroll
                    for (int nt = 0; nt < 4; ++nt)
                        sv[nt] = sf[nt][r] + a2t + c_nt[nt];   // base-2 score
                    if (masked) {
#pragma unroll
                        for (int nt = 0; nt < 4; ++nt) {
                            int kpos = kv0 + nt * 16 + lr;
                            if (kpos > qpos) sv[nt] = -3.0e38f;
                        }
                    }
                    bool over = (sv[0] > m[r]) | (sv[1] > m[r]) | (sv[2] > m[r]) | (sv[3] > m[r]);
                    if (__any(over)) {
                        float mx = fmaxf(fmaxf(sv[0], sv[1]), fmaxf(sv[2], sv[3]));
#pragma unroll
                        for (int off = 1; off < 16; off <<= 1) mx = fmaxf(mx, __shfl_xor(mx, off));
                        float mn = fmaxf(m[r], mx);
                        float rs = exp2f(m[r] - mn);
                        lsum[r] *= rs;
#pragma unroll
                        for (int dt = 0; dt < 8; ++dt) po[dt][r] *= rs;
                        m[r] = mn;
                    }
#pragma unroll
                    for (int nt = 0; nt < 4; ++nt) {
                        float pp = exp2f(sv[nt] - m[r]);
                        lsum[r] += pp;
                        Plds[wave][lg * 4 + r][nt * 16 + lr] = f2bf(pp);
                    }
                }
            }

            __syncthreads();   // barrier 1: V(t) (and K(t-1)) staged

            if (active) {
                short8 pf0 = *(const short8*)&Plds[wave][lr][lg * 8];
                short8 pf1 = *(const short8*)&Plds[wave][lr][32 + lg * 8];
                __builtin_amdgcn_s_setprio(1);
#pragma unroll
                for (int dt = 0; dt < 8; ++dt) {
                    int vrow = dt * 16 + lr;
                    short8 vf0 = *(const short8*)&sV[vrow * 64 + (((lg    ) ^ (vrow & 7)) * 8)];
                    short8 vf1 = *(const short8*)&sV[vrow * 64 + (((lg + 4) ^ (vrow & 7)) * 8)];
                    po[dt] = __builtin_amdgcn_mfma_f32_16x16x32_bf16(pf0, vf0, po[dt], 0, 0, 0);
                    po[dt] = __builtin_amdgcn_mfma_f32_16x16x32_bf16(pf1, vf1, po[dt], 0, 0, 0);
                }
                __builtin_amdgcn_s_setprio(0);
            }

            __syncthreads();   // barrier 2: sV and sK[cur] free for next iteration
            cur ^= 1;
        }

        if (!split) {
#pragma unroll
            for (int r = 0; r < 4; ++r) {
                float sum = lsum[r];
#pragma unroll
                for (int off = 1; off < 16; off <<= 1) sum += __shfl_xor(sum, off);
                float inv = 1.0f / sum;
                int row = q0 + lg * 4 + r;
#pragma unroll
                for (int dt = 0; dt < 8; ++dt)
                    Y[((size_t)(b * SEQ + row)) * EMBD + h * HD + dt * 16 + lr] = f2bf(po[dt][r] * inv);
            }
        } else {
            int jslot = b * 48 + (h - 10) * 8 + (p - 8);
            float* pw = part + (size_t)(jslot * 2 + c) * (128 * 130);
#pragma unroll
            for (int r = 0; r < 4; ++r) {
                float sum = lsum[r];
#pragma unroll
                for (int off = 1; off < 16; off <<= 1) sum += __shfl_xor(sum, off);
                int rr = wave * 16 + lg * 4 + r;
#pragma unroll
                for (int dt = 0; dt < 8; ++dt)
                    pw[rr * 130 + dt * 16 + lr] = po[dt][r];
                if (lr == 0) { pw[rr * 130 + 128] = m[r]; pw[rr * 130 + 129] = sum; }
            }
        }
    }
}

// ---------------- combine partial chunks (96 split units x 128 rows) ----------
__global__ void attn_combine(const float* __restrict__ part, short* __restrict__ Y) {
    const int tid = threadIdx.x;
    const int rg  = blockIdx.x * 2 + (tid >> 7);   // 0..12287
    const int col = tid & 127;
    const int j = rg >> 7, rr = rg & 127;
    const int b = j / 48; const int r2 = j % 48;
    const int h = 10 + r2 / 8, p = 8 + r2 % 8;

    const float* p0 = part + ((size_t)(j * 2) * 128 + rr) * 130;
    const float* p1 = p0 + 128 * 130;
    float m0 = p0[128], l0 = p0[129];
    float m1 = p1[128], l1 = p1[129];
    float M = fmaxf(m0, m1);
    float s0 = exp2f(m0 - M), s1 = exp2f(m1 - M);
    float v = (p0[col] * s0 + p1[col] * s1) / (l0 * s0 + l1 * s1);

    const int w = rr >> 4, i2 = rr & 15;
    const int grow = (w < 4 ? (2 * p + 1) : (2 * p)) * 64 + (w & 3) * 16 + i2;
    Y[((size_t)(b * SEQ + grow)) * EMBD + h * HD + col] = f2bf(v);
}

// ---------------- launch ----------------
extern "C" void kernel_launch(void* const* d_in, const int* in_sizes, int n_in,
                              void* d_out, int out_size, void* d_ws, size_t ws_size,
                              hipStream_t stream) {
    const float* x   = (const float*)d_in[0];
    const float* q_w = (const float*)d_in[1];
    const float* k_w = (const float*)d_in[2];
    const float* v_w = (const float*)d_in[3];
    const float* o_w = (const float*)d_in[4];
    float* out = (float*)d_out;

    char* ws = (char*)d_ws;
    short* x_bf  = (short*)(ws);                       // 4096x2048      16.8MB
    short* w_all = (short*)(ws + 16777216);            // 3072x2048      12.6MB
    short* o_wb  = (short*)(ws + 29360128);            // 2048x2048       8.4MB
    short* q_b   = (short*)(ws + 37748736);            // [2,16,2048,128] 16.8MB
    short* k_b   = (short*)(ws + 54525952);            // [2,4,2048,128]  4.2MB
    short* vT_b  = (short*)(ws + 58720256);            // [2,4,128,2048]  4.2MB
    short* y_b   = (short*)(ws + 62914560);            // 4096x2048      16.8MB
    int*   qtab  = (int*)(ws);                         // queue (dead x_bf region)
    float* part  = (float*)(ws + 65536);               // partials: 12.8MB, same hole

    cvt_all<<<18432, 256, 0, stream>>>(x, q_w, k_w, v_w, o_w, x_bf, w_all, o_wb);

    gemm_bt<0><<<dim3(NQKV / 128, 4096 / 128), 256, 0, stream>>>(
        x_bf, w_all, nullptr, 4096, NQKV, EMBD, q_b, k_b, vT_b);

    attn_setup<<<1, 640, 0, stream>>>(qtab);           // after gemm<0>: x_bf dead
    attn_fwd<<<512, 512, 0, stream>>>(q_b, k_b, vT_b, y_b, part, qtab);
    attn_combine<<<6144, 256, 0, stream>>>(part, y_b);

    gemm_bt<1><<<dim3(EMBD / 128, 4096 / 128), 256, 0, stream>>>(
        y_b, o_wb, out, 4096, EMBD, EMBD, nullptr, nullptr, nullptr);
}

// Round 18
// 200.513 us; speedup vs baseline: 1.0896x; 1.0804x over previous
//
#include <hip/hip_runtime.h>
#include <hip/hip_bf16.h>
#include <math.h>

#define SEQ   2048
#define EMBD  2048
#define NH    16
#define NKV   4
#define HD    128
#define NQKV  3072
#define NUNITS 608        // 512 strip-pair units + 96 second-chunks of split units

typedef __attribute__((ext_vector_type(8))) short short8;
typedef __attribute__((ext_vector_type(4))) short short4v;
typedef __attribute__((ext_vector_type(4))) float floatx4;

static __device__ __forceinline__ short f2bf(float f) {
    union { float f; unsigned u; } cv; cv.f = f;
    unsigned u = cv.u;
    u += 0x7FFF + ((u >> 16) & 1);   // round-to-nearest-even
    return (short)(u >> 16);
}

// async global->LDS, 16B per lane. LDS dest = wave-uniform base + lane*16.
#define GL16(gsrc, ldst)                                                        \
    __builtin_amdgcn_global_load_lds(                                           \
        (const __attribute__((address_space(1))) void*)(gsrc),                  \
        (__attribute__((address_space(3))) void*)(ldst), 16, 0, 0)

// ALiBi window in 64-tiles: truncated mass beyond W is < ~0.2% relative
static __device__ __forceinline__ int alibi_window(float slope2) {
    return (int)ceilf((32.0f / slope2 + 63.0f) * (1.0f / 64.0f));
}

// ---------------- fused fp32 -> bf16 convert (all 5 tensors, one launch) ------
__global__ void cvt_all(const float* __restrict__ x,  const float* __restrict__ qw,
                        const float* __restrict__ kw, const float* __restrict__ vw,
                        const float* __restrict__ ow,
                        short* __restrict__ xb, short* __restrict__ wall,
                        short* __restrict__ owb) {
    int i = blockIdx.x * blockDim.x + threadIdx.x;   // quad index, < 4718592
    const float* src; short* dst; int off;
    if (i < 2097152)      { src = x;  dst = xb;             off = i; }
    else if (i < 3145728) { src = qw; dst = wall;           off = i - 2097152; }
    else if (i < 3407872) { src = kw; dst = wall + 4194304; off = i - 3145728; }
    else if (i < 3670016) { src = vw; dst = wall + 5242880; off = i - 3407872; }
    else                  { src = ow; dst = owb;            off = i - 3670016; }
    float4 v = ((const float4*)src)[off];
    float a[4] = {v.x, v.y, v.z, v.w};
    short4v o;
#pragma unroll
    for (int j = 0; j < 4; ++j) {
        float f = a[j];
        f = isnan(f) ? 0.0f : fminf(fmaxf(f, -10000.0f), 10000.0f);
        o[j] = f2bf(f);
    }
    ((short4v*)dst)[off] = o;
}

// ---------------- bf16 GEMM: 128x128 tile, BK=64, swizzled LDS (R15) ----------
// global_load_lds staging with pre-XORed source (seg^(row&7) on 16B chunks);
// fragment ds_read_b128 XORs the same way -> 2-way (free) bank access.
// Single-buffered: cross-block TLP (4 blocks/CU at 32KB LDS) hides the drain.
// MODE 0: scatter epilogue -> Q (pre-scaled by scale*log2e), K, VT (bf16)
// MODE 1: plain fp32 store
template<int MODE>
__global__ __launch_bounds__(256) void gemm_bt(
    const short* __restrict__ A, const short* __restrict__ W,
    float* __restrict__ Cout, int M, int N, int K,
    short* __restrict__ qb, short* __restrict__ kb, short* __restrict__ vb)
{
    __shared__ __align__(16) short sA[128 * 64];
    __shared__ __align__(16) short sB[128 * 64];

    const int tid  = threadIdx.x;
    const int lane = tid & 63;
    const int wv   = tid >> 6;
    const int wr   = wv >> 1, wc = wv & 1;       // 2x2 wave grid, 64x64 each
    const int lr   = lane & 15, lg = lane >> 4;
    const int bn   = blockIdx.x, bm = blockIdx.y;

    // staging: 1024 chunks(16B) per matrix; wave w covers [w*256, w*256+256)
    const short* gA[4]; const short* gB[4];
    short* lA[4]; short* lB[4];
#pragma unroll
    for (int s = 0; s < 4; ++s) {
        int ck  = wv * 256 + s * 64 + lane;
        int row = ck >> 3, seg = ck & 7;         // 8x16B chunks per 64-short row
        int segSw = seg ^ (row & 7);             // pre-swizzled source column
        gA[s] = A + (size_t)(bm * 128 + row) * K + segSw * 8;
        gB[s] = W + (size_t)(bn * 128 + row) * K + segSw * 8;
        lA[s] = &sA[(wv * 256 + s * 64) * 8];    // linear dest
        lB[s] = &sB[(wv * 256 + s * 64) * 8];
    }

    floatx4 acc[4][4] = {};
    const int nkt = K / 64;
    for (int kt = 0; kt < nkt; ++kt) {
#pragma unroll
        for (int s = 0; s < 4; ++s) {
            GL16(gA[s] + kt * 64, lA[s]);
            GL16(gB[s] + kt * 64, lB[s]);
        }
        __syncthreads();

#pragma unroll
        for (int ks = 0; ks < 2; ++ks) {
            short8 af[4], bfr[4];
#pragma unroll
            for (int i = 0; i < 4; ++i) {
                int ra = wr * 64 + i * 16 + lr;
                int rb = wc * 64 + i * 16 + lr;
                af[i]  = *(const short8*)&sA[ra * 64 + (((ks * 4 + lg) ^ (ra & 7)) * 8)];
                bfr[i] = *(const short8*)&sB[rb * 64 + (((ks * 4 + lg) ^ (rb & 7)) * 8)];
            }
#pragma unroll
            for (int i = 0; i < 4; ++i)
#pragma unroll
                for (int j = 0; j < 4; ++j)
                    acc[i][j] = __builtin_amdgcn_mfma_f32_16x16x32_bf16(af[i], bfr[j], acc[i][j], 0, 0, 0);
        }
        __syncthreads();
    }

    const float QSCALE = 0.08838834764831845f * 1.44269504f;  // scale * log2e
#pragma unroll
    for (int i = 0; i < 4; ++i)
#pragma unroll
        for (int j = 0; j < 4; ++j)
#pragma unroll
            for (int r = 0; r < 4; ++r) {
                int gm = bm * 128 + wr * 64 + i * 16 + lg * 4 + r;
                int gn = bn * 128 + wc * 64 + j * 16 + lr;
                float v = acc[i][j][r];
                if (MODE == 0) {
                    int b = gm >> 11, t = gm & (SEQ - 1);
                    if (gn < 2048) {
                        int h = gn >> 7, d = gn & 127;
                        qb[(((size_t)(b * NH + h)) * SEQ + t) * HD + d] = f2bf(v * QSCALE);
                    } else if (gn < 2560) {
                        int hk = (gn - 2048) >> 7, d = gn & 127;
                        kb[(((size_t)(b * NKV + hk)) * SEQ + t) * HD + d] = f2bf(v);
                    } else {
                        int hv = (gn - 2560) >> 7, d = gn & 127;
                        vb[(((size_t)(b * NKV + hv)) * HD + d) * SEQ + t] = f2bf(v);
                    }
                } else {
                    Cout[(size_t)gm * N + gn] = v;
                }
            }
}

// ---------------- flash attention: persistent queue + split heavy units -------
// 512 persistent blocks (8 waves, 70.1KB LDS -> 2/CU, all resident). Each block
// builds the 608-entry cost-sorted unit table in its own LDS at start (~1-2us,
// parallel; replaces the old attn_setup launch), then pulls units via a global
// counter (zeroed by hipMemsetAsync). Heavy units pre-split into 2 KV chunks
// (fp32 partials -> attn_combine). Tile body identical to R13-R15 (verified).
__global__ __launch_bounds__(512, 4) void attn_fwd(
    const short* __restrict__ Q, const short* __restrict__ Kg,
    const short* __restrict__ VT, short* __restrict__ Y,
    float* __restrict__ part, int* __restrict__ qcnt)
{
    __shared__ __align__(16) short sK[2][64 * 128];   // 32 KB, swizzled chunks
    __shared__ __align__(16) short sV[128 * 64];      // 16 KB, swizzled chunks
    __shared__ short Plds[8][16][72];                 // 18 KB
    __shared__ int sQtab[NUNITS];                     // 2.4 KB
    __shared__ int s_unit;

    const int tid  = threadIdx.x;
    const int wave = tid >> 6, lane = tid & 63;
    const int lr = lane & 15, lg = lane >> 4;

    // ---- build cost-sorted unit table in LDS (same math as old attn_setup) ----
    {
        int myenc[2], mykey[2];
#pragma unroll
        for (int s = 0; s < 2; ++s) {
            int i = tid + s * 512;
            myenc[s] = 0; mykey[s] = 0;
            if (i < NUNITS) {
                int b, h, p, c;
                if (i < 512) { b = i >> 8; h = (i >> 4) & 15; p = i & 15; c = 0; }
                else { int j = i - 512; b = j / 48; int r2 = j % 48; h = 10 + r2 / 8; p = 8 + r2 % 8; c = 1; }
                float slope2 = exp2f(-0.5f * (float)(h + 1)) * 1.44269504f;
                int W = alibi_window(slope2);
                int L = min(W + 1, 2 * p + 2);
                bool split = (h >= 10) && (p >= 8);
                int n0 = (L + 1) >> 1;
                int cost = split ? (c == 0 ? n0 : L - n0) : L;
                myenc[s] = (c << 9) | (b << 8) | (h << 4) | p;
                mykey[s] = cost * 1024 + i;
                sQtab[i] = mykey[s];             // keys first
            }
        }
        __syncthreads();
        int myrank[2] = {-1, -1};
#pragma unroll
        for (int s = 0; s < 2; ++s) {
            int i = tid + s * 512;
            if (i < NUNITS) {
                int rank = 0;
                for (int j = 0; j < NUNITS; ++j) rank += (sQtab[j] > mykey[s]);
                myrank[s] = rank;
            }
        }
        __syncthreads();                          // all key reads done
#pragma unroll
        for (int s = 0; s < 2; ++s)
            if (myrank[s] >= 0) sQtab[myrank[s]] = myenc[s];
        __syncthreads();
    }

    int lOff[2];
#pragma unroll
    for (int j = 0; j < 2; ++j)
        lOff[j] = (wave * 128 + j * 64 + lane) * 8;   // lane-linear, 16B chunks

    for (;;) {
        if (tid == 0) {
            int r = atomicAdd(qcnt, 1);
            s_unit = (r < NUNITS) ? sQtab[r] : -1;
        }
        __syncthreads();
        const int enc = s_unit;
        __syncthreads();
        if (enc < 0) break;

        const int c = (enc >> 9) & 1, b = (enc >> 8) & 1;
        const int h = (enc >> 4) & 15, p = enc & 15;
        const int hkv = h >> 2;               // repeat_interleave: head h -> kv h/4
        const int qgw = 2 * p + (wave < 4 ? 1 : 0);   // this wave's strip

        const short* Qb = Q  +  ((size_t)(b * NH  + h  )) * SEQ * HD;
        const short* Kp = Kg +  ((size_t)(b * NKV + hkv)) * SEQ * HD;
        const short* Vp = VT +  ((size_t)(b * NKV + hkv)) * HD * SEQ;

        const float slope2 = exp2f(-0.5f * (float)(h + 1)) * 1.44269504f;
        const int W = alibi_window(slope2);
        const int thi = 2 * p + 1;
        const int L = min(W + 1, 2 * p + 2);
        const bool split = (h >= 10) && (p >= 8);
        const int n0 = (L + 1) >> 1;
        int t1, t0;
        if (!split)      { t1 = thi;      t0 = thi - L + 1; }
        else if (c == 0) { t1 = thi;      t0 = thi - n0 + 1; }
        else             { t1 = thi - n0; t0 = thi - L + 1; }

        const short* gK[2]; const short* gV[2];
#pragma unroll
        for (int j = 0; j < 2; ++j) {
            int ck = wave * 128 + j * 64 + lane;
            int krow = ck >> 4, kseg = ck & 15;
            gK[j] = Kp + (size_t)krow * HD + (kseg ^ (krow & 7)) * 8;   // pre-swz src
            int vrow = ck >> 3, vseg = ck & 7;
            gV[j] = Vp + (size_t)vrow * SEQ + (vseg ^ (vrow & 7)) * 8;
        }

        float c_nt[4];
#pragma unroll
        for (int nt = 0; nt < 4; ++nt) c_nt[nt] = slope2 * (float)(nt * 16 + lr);

        const int q0 = qgw * 64 + (wave & 3) * 16;
        short8 qf[4];
#pragma unroll
        for (int cc = 0; cc < 4; ++cc)
            qf[cc] = *(const short8*)&Qb[(size_t)(q0 + lr) * HD + cc * 32 + lg * 8];

        floatx4 po[8] = {};
        float m[4], lsum[4];
#pragma unroll
        for (int r = 0; r < 4; ++r) { m[r] = -3.0e38f; lsum[r] = 0.0f; }

        int cur = 0;
        // prologue: stage K(t1)
#pragma unroll
        for (int j = 0; j < 2; ++j)
            GL16(gK[j] + (size_t)(t1 << 6) * HD, &sK[0][0] + lOff[j]);
        __syncthreads();

#pragma unroll 1
        for (int t = t1; t >= t0; --t) {
            // stage V(t); prefetch K(t-1) into other K buffer
#pragma unroll
            for (int j = 0; j < 2; ++j)
                GL16(gV[j] + (t << 6), &sV[0] + lOff[j]);
            if (t > t0) {
#pragma unroll
                for (int j = 0; j < 2; ++j)
                    GL16(gK[j] + (size_t)((t - 1) << 6) * HD, &sK[cur ^ 1][0] + lOff[j]);
            }

            const bool active = (t <= qgw) && (t > qgw - W);
            const int kv0 = t << 6;

            if (active) {
                const short* kr = &sK[cur][0];
                floatx4 sf[4];
                __builtin_amdgcn_s_setprio(1);
#pragma unroll
                for (int nt = 0; nt < 4; ++nt) {
                    floatx4 sacc = {0.f, 0.f, 0.f, 0.f};
#pragma unroll
                    for (int cc = 0; cc < 4; ++cc) {
                        int krow = nt * 16 + lr;
                        short8 kf = *(const short8*)&kr[krow * 128 + (((cc * 4 + lg) ^ (krow & 7)) * 8)];
                        sacc = __builtin_amdgcn_mfma_f32_16x16x32_bf16(qf[cc], kf, sacc, 0, 0, 0);
                    }
                    sf[nt] = sacc;
                }
                __builtin_amdgcn_s_setprio(0);

                const float a2t = slope2 * (float)kv0;
                const bool masked = (t == qgw);
#pragma unroll
                for (int r = 0; r < 4; ++r) {
                    const int qpos = q0 + lg * 4 + r;
                    float sv[4];
#pragma unroll
                    for (int nt = 0; nt < 4; ++nt)
                        sv[nt] = sf[nt][r] + a2t + c_nt[nt];   // base-2 score
                    if (masked) {
#pragma unroll
                        for (int nt = 0; nt < 4; ++nt) {
                            int kpos = kv0 + nt * 16 + lr;
                            if (kpos > qpos) sv[nt] = -3.0e38f;
                        }
                    }
                    bool over = (sv[0] > m[r]) | (sv[1] > m[r]) | (sv[2] > m[r]) | (sv[3] > m[r]);
                    if (__any(over)) {
                        float mx = fmaxf(fmaxf(sv[0], sv[1]), fmaxf(sv[2], sv[3]));
#pragma unroll
                        for (int off = 1; off < 16; off <<= 1) mx = fmaxf(mx, __shfl_xor(mx, off));
                        float mn = fmaxf(m[r], mx);
                        float rs = exp2f(m[r] - mn);
                        lsum[r] *= rs;
#pragma unroll
                        for (int dt = 0; dt < 8; ++dt) po[dt][r] *= rs;
                        m[r] = mn;
                    }
#pragma unroll
                    for (int nt = 0; nt < 4; ++nt) {
                        float pp = exp2f(sv[nt] - m[r]);
                        lsum[r] += pp;
                        Plds[wave][lg * 4 + r][nt * 16 + lr] = f2bf(pp);
                    }
                }
            }

            __syncthreads();   // barrier 1: V(t) (and K(t-1)) staged

            if (active) {
                short8 pf0 = *(const short8*)&Plds[wave][lr][lg * 8];
                short8 pf1 = *(const short8*)&Plds[wave][lr][32 + lg * 8];
                __builtin_amdgcn_s_setprio(1);
#pragma unroll
                for (int dt = 0; dt < 8; ++dt) {
                    int vrow = dt * 16 + lr;
                    short8 vf0 = *(const short8*)&sV[vrow * 64 + (((lg    ) ^ (vrow & 7)) * 8)];
                    short8 vf1 = *(const short8*)&sV[vrow * 64 + (((lg + 4) ^ (vrow & 7)) * 8)];
                    po[dt] = __builtin_amdgcn_mfma_f32_16x16x32_bf16(pf0, vf0, po[dt], 0, 0, 0);
                    po[dt] = __builtin_amdgcn_mfma_f32_16x16x32_bf16(pf1, vf1, po[dt], 0, 0, 0);
                }
                __builtin_amdgcn_s_setprio(0);
            }

            __syncthreads();   // barrier 2: sV and sK[cur] free for next iteration
            cur ^= 1;
        }

        if (!split) {
#pragma unroll
            for (int r = 0; r < 4; ++r) {
                float sum = lsum[r];
#pragma unroll
                for (int off = 1; off < 16; off <<= 1) sum += __shfl_xor(sum, off);
                float inv = 1.0f / sum;
                int row = q0 + lg * 4 + r;
#pragma unroll
                for (int dt = 0; dt < 8; ++dt)
                    Y[((size_t)(b * SEQ + row)) * EMBD + h * HD + dt * 16 + lr] = f2bf(po[dt][r] * inv);
            }
        } else {
            int jslot = b * 48 + (h - 10) * 8 + (p - 8);
            float* pw = part + (size_t)(jslot * 2 + c) * (128 * 130);
#pragma unroll
            for (int r = 0; r < 4; ++r) {
                float sum = lsum[r];
#pragma unroll
                for (int off = 1; off < 16; off <<= 1) sum += __shfl_xor(sum, off);
                int rr = wave * 16 + lg * 4 + r;
#pragma unroll
                for (int dt = 0; dt < 8; ++dt)
                    pw[rr * 130 + dt * 16 + lr] = po[dt][r];
                if (lr == 0) { pw[rr * 130 + 128] = m[r]; pw[rr * 130 + 129] = sum; }
            }
        }
    }
}

// ---------------- combine partial chunks (96 split units x 128 rows) ----------
__global__ void attn_combine(const float* __restrict__ part, short* __restrict__ Y) {
    const int tid = threadIdx.x;
    const int rg  = blockIdx.x * 2 + (tid >> 7);   // 0..12287
    const int col = tid & 127;
    const int j = rg >> 7, rr = rg & 127;
    const int b = j / 48; const int r2 = j % 48;
    const int h = 10 + r2 / 8, p = 8 + r2 % 8;

    const float* p0 = part + ((size_t)(j * 2) * 128 + rr) * 130;
    const float* p1 = p0 + 128 * 130;
    float m0 = p0[128], l0 = p0[129];
    float m1 = p1[128], l1 = p1[129];
    float M = fmaxf(m0, m1);
    float s0 = exp2f(m0 - M), s1 = exp2f(m1 - M);
    float v = (p0[col] * s0 + p1[col] * s1) / (l0 * s0 + l1 * s1);

    const int w = rr >> 4, i2 = rr & 15;
    const int grow = (w < 4 ? (2 * p + 1) : (2 * p)) * 64 + (w & 3) * 16 + i2;
    Y[((size_t)(b * SEQ + grow)) * EMBD + h * HD + col] = f2bf(v);
}

// ---------------- launch ----------------
extern "C" void kernel_launch(void* const* d_in, const int* in_sizes, int n_in,
                              void* d_out, int out_size, void* d_ws, size_t ws_size,
                              hipStream_t stream) {
    const float* x   = (const float*)d_in[0];
    const float* q_w = (const float*)d_in[1];
    const float* k_w = (const float*)d_in[2];
    const float* v_w = (const float*)d_in[3];
    const float* o_w = (const float*)d_in[4];
    float* out = (float*)d_out;

    char* ws = (char*)d_ws;
    short* x_bf  = (short*)(ws);                       // 4096x2048      16.8MB
    short* w_all = (short*)(ws + 16777216);            // 3072x2048      12.6MB
    short* o_wb  = (short*)(ws + 29360128);            // 2048x2048       8.4MB
    short* q_b   = (short*)(ws + 37748736);            // [2,16,2048,128] 16.8MB
    short* k_b   = (short*)(ws + 54525952);            // [2,4,2048,128]  4.2MB
    short* vT_b  = (short*)(ws + 58720256);            // [2,4,128,2048]  4.2MB
    short* y_b   = (short*)(ws + 62914560);            // 4096x2048      16.8MB
    int*   qcnt  = (int*)(ws);                         // pull counter (dead x_bf)
    float* part  = (float*)(ws + 65536);               // partials: 12.8MB, same hole

    cvt_all<<<18432, 256, 0, stream>>>(x, q_w, k_w, v_w, o_w, x_bf, w_all, o_wb);

    gemm_bt<0><<<dim3(NQKV / 128, 4096 / 128), 256, 0, stream>>>(
        x_bf, w_all, nullptr, 4096, NQKV, EMBD, q_b, k_b, vT_b);

    hipMemsetAsync(qcnt, 0, 4, stream);                // after gemm<0>: x_bf dead
    attn_fwd<<<512, 512, 0, stream>>>(q_b, k_b, vT_b, y_b, part, qcnt);
    attn_combine<<<6144, 256, 0, stream>>>(part, y_b);

    gemm_bt<1><<<dim3(EMBD / 128, 4096 / 128), 256, 0, stream>>>(
        y_b, o_wb, out, 4096, EMBD, EMBD, nullptr, nullptr, nullptr);
}

// Round 19
// 193.700 us; speedup vs baseline: 1.1279x; 1.0352x over previous
//
#include <hip/hip_runtime.h>
#include <hip/hip_bf16.h>
#include <math.h>

#define SEQ   2048
#define EMBD  2048
#define NH    16
#define NKV   4
#define HD    128
#define NQKV  3072
#define NUNITS 608        // 512 strip-pair units + 96 second-chunks of split units

typedef __attribute__((ext_vector_type(8))) short short8;
typedef __attribute__((ext_vector_type(4))) short short4v;
typedef __attribute__((ext_vector_type(4))) float floatx4;

static __device__ __forceinline__ short f2bf(float f) {
    union { float f; unsigned u; } cv; cv.f = f;
    unsigned u = cv.u;
    u += 0x7FFF + ((u >> 16) & 1);   // round-to-nearest-even
    return (short)(u >> 16);
}

// async global->LDS, 16B per lane. LDS dest = wave-uniform base + lane*16.
#define GL16(gsrc, ldst)                                                        \
    __builtin_amdgcn_global_load_lds(                                           \
        (const __attribute__((address_space(1))) void*)(gsrc),                  \
        (__attribute__((address_space(3))) void*)(ldst), 16, 0, 0)

// ALiBi window in 64-tiles: truncated mass beyond W is < ~0.2% relative
static __device__ __forceinline__ int alibi_window(float slope2) {
    return (int)ceilf((32.0f / slope2 + 63.0f) * (1.0f / 64.0f));
}

// ---------------- compile-time cost-sorted unit table -------------------------
// Unit order is a pure function of shape; only scheduling (not correctness)
// depends on it: kernel derives its own bounds from (c,b,h,p). W_TAB mirrors
// alibi_window(slope2(h)) for h=0..15.
struct QTab { int v[NUNITS]; };
static constexpr int W_TAB[16] = {2,2,2,3,3,4,5,7,9,13,17,24,33,46,64,90};
static constexpr QTab make_qtab() {
    QTab t{};
    int cost[NUNITS] = {}, enc[NUNITS] = {};
    for (int i = 0; i < NUNITS; ++i) {
        int b, h, p, c;
        if (i < 512) { b = i >> 8; h = (i >> 4) & 15; p = i & 15; c = 0; }
        else { int j = i - 512; b = j / 48; int r2 = j % 48; h = 10 + r2 / 8; p = 8 + r2 % 8; c = 1; }
        int W = W_TAB[h];
        int L = (W + 1 < 2 * p + 2) ? (W + 1) : (2 * p + 2);
        int n0 = (L + 1) >> 1;
        bool split = (h >= 10) && (p >= 8);
        cost[i] = split ? (c == 0 ? n0 : L - n0) : L;
        enc[i] = (c << 9) | (b << 8) | (h << 4) | p;
    }
    int idx = 0;
    for (int cval = 32; cval >= 1; --cval)          // counting sort, cost desc
        for (int i = NUNITS - 1; i >= 0; --i)       // larger i first (matches old key)
            if (cost[i] == cval) t.v[idx++] = enc[i];
    return t;
}
static __constant__ QTab d_qt = make_qtab();

// ---------------- fused fp32 -> bf16 convert (all 5 tensors, one launch) ------
__global__ void cvt_all(const float* __restrict__ x,  const float* __restrict__ qw,
                        const float* __restrict__ kw, const float* __restrict__ vw,
                        const float* __restrict__ ow,
                        short* __restrict__ xb, short* __restrict__ wall,
                        short* __restrict__ owb) {
    int i = blockIdx.x * blockDim.x + threadIdx.x;   // quad index, < 4718592
    const float* src; short* dst; int off;
    if (i < 2097152)      { src = x;  dst = xb;             off = i; }
    else if (i < 3145728) { src = qw; dst = wall;           off = i - 2097152; }
    else if (i < 3407872) { src = kw; dst = wall + 4194304; off = i - 3145728; }
    else if (i < 3670016) { src = vw; dst = wall + 5242880; off = i - 3407872; }
    else                  { src = ow; dst = owb;            off = i - 3670016; }
    float4 v = ((const float4*)src)[off];
    float a[4] = {v.x, v.y, v.z, v.w};
    short4v o;
#pragma unroll
    for (int j = 0; j < 4; ++j) {
        float f = a[j];
        f = isnan(f) ? 0.0f : fminf(fmaxf(f, -10000.0f), 10000.0f);
        o[j] = f2bf(f);
    }
    ((short4v*)dst)[off] = o;
}

// ---------------- bf16 GEMM: 128x128 tile, BK=64, swizzled LDS (R15) ----------
// global_load_lds staging with pre-XORed source (seg^(row&7) on 16B chunks);
// fragment ds_read_b128 XORs the same way -> 2-way (free) bank access.
// Single-buffered: cross-block TLP (4 blocks/CU at 32KB LDS) hides the drain.
// MODE 0: scatter epilogue -> Q (pre-scaled by scale*log2e), K, VT (bf16)
// MODE 1: plain fp32 store
template<int MODE>
__global__ __launch_bounds__(256) void gemm_bt(
    const short* __restrict__ A, const short* __restrict__ W,
    float* __restrict__ Cout, int M, int N, int K,
    short* __restrict__ qb, short* __restrict__ kb, short* __restrict__ vb)
{
    __shared__ __align__(16) short sA[128 * 64];
    __shared__ __align__(16) short sB[128 * 64];

    const int tid  = threadIdx.x;
    const int lane = tid & 63;
    const int wv   = tid >> 6;
    const int wr   = wv >> 1, wc = wv & 1;       // 2x2 wave grid, 64x64 each
    const int lr   = lane & 15, lg = lane >> 4;
    const int bn   = blockIdx.x, bm = blockIdx.y;

    // staging: 1024 chunks(16B) per matrix; wave w covers [w*256, w*256+256)
    const short* gA[4]; const short* gB[4];
    short* lA[4]; short* lB[4];
#pragma unroll
    for (int s = 0; s < 4; ++s) {
        int ck  = wv * 256 + s * 64 + lane;
        int row = ck >> 3, seg = ck & 7;         // 8x16B chunks per 64-short row
        int segSw = seg ^ (row & 7);             // pre-swizzled source column
        gA[s] = A + (size_t)(bm * 128 + row) * K + segSw * 8;
        gB[s] = W + (size_t)(bn * 128 + row) * K + segSw * 8;
        lA[s] = &sA[(wv * 256 + s * 64) * 8];    // linear dest
        lB[s] = &sB[(wv * 256 + s * 64) * 8];
    }

    floatx4 acc[4][4] = {};
    const int nkt = K / 64;
    for (int kt = 0; kt < nkt; ++kt) {
#pragma unroll
        for (int s = 0; s < 4; ++s) {
            GL16(gA[s] + kt * 64, lA[s]);
            GL16(gB[s] + kt * 64, lB[s]);
        }
        __syncthreads();

#pragma unroll
        for (int ks = 0; ks < 2; ++ks) {
            short8 af[4], bfr[4];
#pragma unroll
            for (int i = 0; i < 4; ++i) {
                int ra = wr * 64 + i * 16 + lr;
                int rb = wc * 64 + i * 16 + lr;
                af[i]  = *(const short8*)&sA[ra * 64 + (((ks * 4 + lg) ^ (ra & 7)) * 8)];
                bfr[i] = *(const short8*)&sB[rb * 64 + (((ks * 4 + lg) ^ (rb & 7)) * 8)];
            }
#pragma unroll
            for (int i = 0; i < 4; ++i)
#pragma unroll
                for (int j = 0; j < 4; ++j)
                    acc[i][j] = __builtin_amdgcn_mfma_f32_16x16x32_bf16(af[i], bfr[j], acc[i][j], 0, 0, 0);
        }
        __syncthreads();
    }

    const float QSCALE = 0.08838834764831845f * 1.44269504f;  // scale * log2e
#pragma unroll
    for (int i = 0; i < 4; ++i)
#pragma unroll
        for (int j = 0; j < 4; ++j)
#pragma unroll
            for (int r = 0; r < 4; ++r) {
                int gm = bm * 128 + wr * 64 + i * 16 + lg * 4 + r;
                int gn = bn * 128 + wc * 64 + j * 16 + lr;
                float v = acc[i][j][r];
                if (MODE == 0) {
                    int b = gm >> 11, t = gm & (SEQ - 1);
                    if (gn < 2048) {
                        int h = gn >> 7, d = gn & 127;
                        qb[(((size_t)(b * NH + h)) * SEQ + t) * HD + d] = f2bf(v * QSCALE);
                    } else if (gn < 2560) {
                        int hk = (gn - 2048) >> 7, d = gn & 127;
                        kb[(((size_t)(b * NKV + hk)) * SEQ + t) * HD + d] = f2bf(v);
                    } else {
                        int hv = (gn - 2560) >> 7, d = gn & 127;
                        vb[(((size_t)(b * NKV + hv)) * HD + d) * SEQ + t] = f2bf(v);
                    }
                } else {
                    Cout[(size_t)gm * N + gn] = v;
                }
            }
}

// ---------------- flash attention: persistent queue + split heavy units -------
// 512 persistent blocks (8 waves, 67.7KB LDS -> 2/CU, all resident). Blocks
// pull units from the compile-time cost-sorted __constant__ table via a global
// counter (zeroed by hipMemsetAsync): online LPT, max grain 17 tiles. Heavy
// units pre-split into 2 KV chunks (fp32 partials -> attn_combine). Tile body
// identical to R13-R15 (verified): dbuf K, single-buffer V, 2 barriers, setprio.
__global__ __launch_bounds__(512, 4) void attn_fwd(
    const short* __restrict__ Q, const short* __restrict__ Kg,
    const short* __restrict__ VT, short* __restrict__ Y,
    float* __restrict__ part, int* __restrict__ qcnt)
{
    __shared__ __align__(16) short sK[2][64 * 128];   // 32 KB, swizzled chunks
    __shared__ __align__(16) short sV[128 * 64];      // 16 KB, swizzled chunks
    __shared__ short Plds[8][16][72];                 // 18 KB
    __shared__ int s_unit;

    const int tid  = threadIdx.x;
    const int wave = tid >> 6, lane = tid & 63;
    const int lr = lane & 15, lg = lane >> 4;

    int lOff[2];
#pragma unroll
    for (int j = 0; j < 2; ++j)
        lOff[j] = (wave * 128 + j * 64 + lane) * 8;   // lane-linear, 16B chunks

    for (;;) {
        if (tid == 0) {
            int r = atomicAdd(qcnt, 1);
            s_unit = (r < NUNITS) ? d_qt.v[r] : -1;
        }
        __syncthreads();
        const int enc = s_unit;
        __syncthreads();
        if (enc < 0) break;

        const int c = (enc >> 9) & 1, b = (enc >> 8) & 1;
        const int h = (enc >> 4) & 15, p = enc & 15;
        const int hkv = h >> 2;               // repeat_interleave: head h -> kv h/4
        const int qgw = 2 * p + (wave < 4 ? 1 : 0);   // this wave's strip

        const short* Qb = Q  +  ((size_t)(b * NH  + h  )) * SEQ * HD;
        const short* Kp = Kg +  ((size_t)(b * NKV + hkv)) * SEQ * HD;
        const short* Vp = VT +  ((size_t)(b * NKV + hkv)) * HD * SEQ;

        const float slope2 = exp2f(-0.5f * (float)(h + 1)) * 1.44269504f;
        const int W = alibi_window(slope2);
        const int thi = 2 * p + 1;
        const int L = min(W + 1, 2 * p + 2);
        const bool split = (h >= 10) && (p >= 8);
        const int n0 = (L + 1) >> 1;
        int t1, t0;
        if (!split)      { t1 = thi;      t0 = thi - L + 1; }
        else if (c == 0) { t1 = thi;      t0 = thi - n0 + 1; }
        else             { t1 = thi - n0; t0 = thi - L + 1; }

        const short* gK[2]; const short* gV[2];
#pragma unroll
        for (int j = 0; j < 2; ++j) {
            int ck = wave * 128 + j * 64 + lane;
            int krow = ck >> 4, kseg = ck & 15;
            gK[j] = Kp + (size_t)krow * HD + (kseg ^ (krow & 7)) * 8;   // pre-swz src
            int vrow = ck >> 3, vseg = ck & 7;
            gV[j] = Vp + (size_t)vrow * SEQ + (vseg ^ (vrow & 7)) * 8;
        }

        float c_nt[4];
#pragma unroll
        for (int nt = 0; nt < 4; ++nt) c_nt[nt] = slope2 * (float)(nt * 16 + lr);

        const int q0 = qgw * 64 + (wave & 3) * 16;
        short8 qf[4];
#pragma unroll
        for (int cc = 0; cc < 4; ++cc)
            qf[cc] = *(const short8*)&Qb[(size_t)(q0 + lr) * HD + cc * 32 + lg * 8];

        floatx4 po[8] = {};
        float m[4], lsum[4];
#pragma unroll
        for (int r = 0; r < 4; ++r) { m[r] = -3.0e38f; lsum[r] = 0.0f; }

        int cur = 0;
        // prologue: stage K(t1)
#pragma unroll
        for (int j = 0; j < 2; ++j)
            GL16(gK[j] + (size_t)(t1 << 6) * HD, &sK[0][0] + lOff[j]);
        __syncthreads();

#pragma unroll 1
        for (int t = t1; t >= t0; --t) {
            // stage V(t); prefetch K(t-1) into other K buffer
#pragma unroll
            for (int j = 0; j < 2; ++j)
                GL16(gV[j] + (t << 6), &sV[0] + lOff[j]);
            if (t > t0) {
#pragma unroll
                for (int j = 0; j < 2; ++j)
                    GL16(gK[j] + (size_t)((t - 1) << 6) * HD, &sK[cur ^ 1][0] + lOff[j]);
            }

            const bool active = (t <= qgw) && (t > qgw - W);
            const int kv0 = t << 6;

            if (active) {
                const short* kr = &sK[cur][0];
                floatx4 sf[4];
                __builtin_amdgcn_s_setprio(1);
#pragma unroll
                for (int nt = 0; nt < 4; ++nt) {
                    floatx4 sacc = {0.f, 0.f, 0.f, 0.f};
#pragma unroll
                    for (int cc = 0; cc < 4; ++cc) {
                        int krow = nt * 16 + lr;
                        short8 kf = *(const short8*)&kr[krow * 128 + (((cc * 4 + lg) ^ (krow & 7)) * 8)];
                        sacc = __builtin_amdgcn_mfma_f32_16x16x32_bf16(qf[cc], kf, sacc, 0, 0, 0);
                    }
                    sf[nt] = sacc;
                }
                __builtin_amdgcn_s_setprio(0);

                const float a2t = slope2 * (float)kv0;
                const bool masked = (t == qgw);
#pragma unroll
                for (int r = 0; r < 4; ++r) {
                    const int qpos = q0 + lg * 4 + r;
                    float sv[4];
#pragma unroll
                    for (int nt = 0; nt < 4; ++nt)
                        sv[nt] = sf[nt][r] + a2t + c_nt[nt];   // base-2 score
                    if (masked) {
#pragma unroll
                        for (int nt = 0; nt < 4; ++nt) {
                            int kpos = kv0 + nt * 16 + lr;
                            if (kpos > qpos) sv[nt] = -3.0e38f;
                        }
                    }
                    bool over = (sv[0] > m[r]) | (sv[1] > m[r]) | (sv[2] > m[r]) | (sv[3] > m[r]);
                    if (__any(over)) {
                        float mx = fmaxf(fmaxf(sv[0], sv[1]), fmaxf(sv[2], sv[3]));
#pragma unroll
                        for (int off = 1; off < 16; off <<= 1) mx = fmaxf(mx, __shfl_xor(mx, off));
                        float mn = fmaxf(m[r], mx);
                        float rs = exp2f(m[r] - mn);
                        lsum[r] *= rs;
#pragma unroll
                        for (int dt = 0; dt < 8; ++dt) po[dt][r] *= rs;
                        m[r] = mn;
                    }
#pragma unroll
                    for (int nt = 0; nt < 4; ++nt) {
                        float pp = exp2f(sv[nt] - m[r]);
                        lsum[r] += pp;
                        Plds[wave][lg * 4 + r][nt * 16 + lr] = f2bf(pp);
                    }
                }
            }

            __syncthreads();   // barrier 1: V(t) (and K(t-1)) staged

            if (active) {
                short8 pf0 = *(const short8*)&Plds[wave][lr][lg * 8];
                short8 pf1 = *(const short8*)&Plds[wave][lr][32 + lg * 8];
                __builtin_amdgcn_s_setprio(1);
#pragma unroll
                for (int dt = 0; dt < 8; ++dt) {
                    int vrow = dt * 16 + lr;
                    short8 vf0 = *(const short8*)&sV[vrow * 64 + (((lg    ) ^ (vrow & 7)) * 8)];
                    short8 vf1 = *(const short8*)&sV[vrow * 64 + (((lg + 4) ^ (vrow & 7)) * 8)];
                    po[dt] = __builtin_amdgcn_mfma_f32_16x16x32_bf16(pf0, vf0, po[dt], 0, 0, 0);
                    po[dt] = __builtin_amdgcn_mfma_f32_16x16x32_bf16(pf1, vf1, po[dt], 0, 0, 0);
                }
                __builtin_amdgcn_s_setprio(0);
            }

            __syncthreads();   // barrier 2: sV and sK[cur] free for next iteration
            cur ^= 1;
        }

        if (!split) {
#pragma unroll
            for (int r = 0; r < 4; ++r) {
                float sum = lsum[r];
#pragma unroll
                for (int off = 1; off < 16; off <<= 1) sum += __shfl_xor(sum, off);
                float inv = 1.0f / sum;
                int row = q0 + lg * 4 + r;
#pragma unroll
                for (int dt = 0; dt < 8; ++dt)
                    Y[((size_t)(b * SEQ + row)) * EMBD + h * HD + dt * 16 + lr] = f2bf(po[dt][r] * inv);
            }
        } else {
            int jslot = b * 48 + (h - 10) * 8 + (p - 8);
            float* pw = part + (size_t)(jslot * 2 + c) * (128 * 130);
#pragma unroll
            for (int r = 0; r < 4; ++r) {
                float sum = lsum[r];
#pragma unroll
                for (int off = 1; off < 16; off <<= 1) sum += __shfl_xor(sum, off);
                int rr = wave * 16 + lg * 4 + r;
#pragma unroll
                for (int dt = 0; dt < 8; ++dt)
                    pw[rr * 130 + dt * 16 + lr] = po[dt][r];
                if (lr == 0) { pw[rr * 130 + 128] = m[r]; pw[rr * 130 + 129] = sum; }
            }
        }
    }
}

// ---------------- combine partial chunks (96 split units x 128 rows) ----------
__global__ void attn_combine(const float* __restrict__ part, short* __restrict__ Y) {
    const int tid = threadIdx.x;
    const int rg  = blockIdx.x * 2 + (tid >> 7);   // 0..12287
    const int col = tid & 127;
    const int j = rg >> 7, rr = rg & 127;
    const int b = j / 48; const int r2 = j % 48;
    const int h = 10 + r2 / 8, p = 8 + r2 % 8;

    const float* p0 = part + ((size_t)(j * 2) * 128 + rr) * 130;
    const float* p1 = p0 + 128 * 130;
    float m0 = p0[128], l0 = p0[129];
    float m1 = p1[128], l1 = p1[129];
    float M = fmaxf(m0, m1);
    float s0 = exp2f(m0 - M), s1 = exp2f(m1 - M);
    float v = (p0[col] * s0 + p1[col] * s1) / (l0 * s0 + l1 * s1);

    const int w = rr >> 4, i2 = rr & 15;
    const int grow = (w < 4 ? (2 * p + 1) : (2 * p)) * 64 + (w & 3) * 16 + i2;
    Y[((size_t)(b * SEQ + grow)) * EMBD + h * HD + col] = f2bf(v);
}

// ---------------- launch ----------------
extern "C" void kernel_launch(void* const* d_in, const int* in_sizes, int n_in,
                              void* d_out, int out_size, void* d_ws, size_t ws_size,
                              hipStream_t stream) {
    const float* x   = (const float*)d_in[0];
    const float* q_w = (const float*)d_in[1];
    const float* k_w = (const float*)d_in[2];
    const float* v_w = (const float*)d_in[3];
    const float* o_w = (const float*)d_in[4];
    float* out = (float*)d_out;

    char* ws = (char*)d_ws;
    short* x_bf  = (short*)(ws);                       // 4096x2048      16.8MB
    short* w_all = (short*)(ws + 16777216);            // 3072x2048      12.6MB
    short* o_wb  = (short*)(ws + 29360128);            // 2048x2048       8.4MB
    short* q_b   = (short*)(ws + 37748736);            // [2,16,2048,128] 16.8MB
    short* k_b   = (short*)(ws + 54525952);            // [2,4,2048,128]  4.2MB
    short* vT_b  = (short*)(ws + 58720256);            // [2,4,128,2048]  4.2MB
    short* y_b   = (short*)(ws + 62914560);            // 4096x2048      16.8MB
    int*   qcnt  = (int*)(ws);                         // pull counter (dead x_bf)
    float* part  = (float*)(ws + 65536);               // partials: 12.8MB, same hole

    cvt_all<<<18432, 256, 0, stream>>>(x, q_w, k_w, v_w, o_w, x_bf, w_all, o_wb);

    gemm_bt<0><<<dim3(NQKV / 128, 4096 / 128), 256, 0, stream>>>(
        x_bf, w_all, nullptr, 4096, NQKV, EMBD, q_b, k_b, vT_b);

    hipMemsetAsync(qcnt, 0, 4, stream);                // after gemm<0>: x_bf dead
    attn_fwd<<<512, 512, 0, stream>>>(q_b, k_b, vT_b, y_b, part, qcnt);
    attn_combine<<<6144, 256, 0, stream>>>(part, y_b);

    gemm_bt<1><<<dim3(EMBD / 128, 4096 / 128), 256, 0, stream>>>(
        y_b, o_wb, out, 4096, EMBD, EMBD, nullptr, nullptr, nullptr);
}